// Round 6
// baseline (504.310 us; speedup 1.0000x reference)
//
#include <hip/hip_runtime.h>
#include <math.h>

#define BB 512
#define NN 200
#define DD 128
#define BNROWS (BB*NN)   // 102400

typedef float f32x4 __attribute__((ext_vector_type(4)));
typedef short bf16x8 __attribute__((ext_vector_type(8)));
typedef unsigned short u16x4 __attribute__((ext_vector_type(4)));

#define MFMA16(a,b,c) __builtin_amdgcn_mfma_f32_16x16x32_bf16(a,b,c,0,0,0)

// async global -> LDS, 16B per lane. LDS dest is WAVE-UNIFORM base; HW adds lane*16.
#define GLL(gp, lp) __builtin_amdgcn_global_load_lds( \
    (const __attribute__((address_space(1))) unsigned int*)(gp), \
    (__attribute__((address_space(3))) unsigned int*)(lp), 16, 0, 0)

#define KWAITV(S) asm volatile("s_waitcnt vmcnt(" S ")" ::: "memory")
#define KWAITL()  asm volatile("s_waitcnt lgkmcnt(0)" ::: "memory")
#define KBAR()    __builtin_amdgcn_s_barrier()
#define KSBAR()   __builtin_amdgcn_sched_barrier(0)

// ---------------- workspace layout (bytes) ----------------
#define OFF_ZHI   ((size_t)0)
#define OFF_ZLO   (OFF_ZHI + (size_t)BNROWS*384*2)
#define OFF_HT    (OFF_ZLO + (size_t)BNROWS*256*2)
#define OFF_M1    (OFF_HT  + (size_t)BB*128*224*2)
#define OFF_M2    (OFF_M1  + (size_t)384*128*4)
#define OFF_WH    (OFF_M2  + (size_t)384*128*4)
#define OFF_WL    (OFF_WH  + (size_t)512*384*2)
#define OFF_CC    (OFF_WL  + (size_t)512*384*2)
#define OFF_U1V   (OFF_CC  + 512*4)
#define OFF_U2V   (OFF_U1V + 512*4)
#define OFF_U1    (OFF_U2V + 512*4)
#define OFF_U2    (OFF_U1  + 384*4)
#define OFF_C0    (OFF_U2  + 384*4)
#define OFF_RSI   (OFF_C0  + 384*4)
#define OFF_RSO   (OFF_RSI + (size_t)BNROWS*4)
#define WS_BYTES  (OFF_RSO + (size_t)BNROWS*4)

__device__ inline unsigned short f2bf(float x) {
  unsigned int u = __float_as_uint(x);
  unsigned int r = u + 0x7FFFu + ((u >> 16) & 1u);   // RNE
  return (unsigned short)(r >> 16);
}
__device__ inline float bf2f(unsigned short h) {
  return __uint_as_float(((unsigned int)h) << 16);
}
__device__ inline float fsigmoid(float x) {
  return 1.f / (1.f + __expf(-x));
}
__device__ inline float ftanh(float x) {
  x = fminf(15.f, fmaxf(-15.f, x));   // avoid inf/inf
  float e = __expf(-2.f * x);
  return (1.f - e) / (1.f + e);
}

// ---------------- kprep: M1 = W1 @ w_in, M2 = W2 @ w_out; u1,u2,c0 vectors ----
__global__ __launch_bounds__(128) void kprep(
    const float* __restrict__ w_ih, const float* __restrict__ w_in,
    const float* __restrict__ w_out, const float* __restrict__ b_in,
    const float* __restrict__ b_out, const float* __restrict__ b_iah,
    const float* __restrict__ b_oah, const float* __restrict__ b_ih,
    float* __restrict__ M1, float* __restrict__ M2,
    float* __restrict__ u1, float* __restrict__ u2, float* __restrict__ c0) {
  __shared__ float wrow[256];
  const int j = blockIdx.x;        // 0..383
  const int k = threadIdx.x;       // 0..127
  wrow[k]       = w_ih[(size_t)j * 256 + k];
  wrow[128 + k] = w_ih[(size_t)j * 256 + 128 + k];
  __syncthreads();
  float a1 = 0.f, a2 = 0.f;
  for (int t = 0; t < 128; ++t) {
    a1 = fmaf(wrow[t],       w_in[t * 128 + k],  a1);
    a2 = fmaf(wrow[128 + t], w_out[t * 128 + k], a2);
  }
  M1[j * 128 + k] = a1;
  M2[j * 128 + k] = a2;
  if (k == 0) {
    float s1 = 0.f, s2 = 0.f, s0 = 0.f;
    for (int t = 0; t < 128; ++t) {
      s1 = fmaf(wrow[t], b_in[t], s1);
      s2 = fmaf(wrow[128 + t], b_out[t], s2);
      s0 = fmaf(wrow[t], b_iah[t], s0);
      s0 = fmaf(wrow[128 + t], b_oah[t], s0);
    }
    u1[j] = s1; u2[j] = s2; c0[j] = s0 + b_ih[j];
  }
}

// ---------------- Wcat build: permuted 512-col [r | i | n_P | n_h], K=384 ------
__global__ void wcat_build(const float* __restrict__ M1, const float* __restrict__ M2,
                           const float* __restrict__ w_hh, const float* __restrict__ b_hh,
                           const float* __restrict__ u1, const float* __restrict__ u2,
                           const float* __restrict__ c0,
                           unsigned short* __restrict__ Wh, unsigned short* __restrict__ Wl,
                           float* __restrict__ cc, float* __restrict__ u1v,
                           float* __restrict__ u2v) {
  int idx = blockIdx.x * 256 + threadIdx.x;   // 512*384
  if (idx >= 512 * 384) return;
  int jp = idx / 384, k = idx - jp * 384;
  int nh = jp >> 8, ng = (jp >> 7) & 1, t = (jp >> 4) & 7, q = jp & 15;
  int blk = t >> 1, s = t & 1;
  int c = nh * 64 + ng * 32 + s * 16 + q;
  int g = (blk <= 1) ? blk : 2;
  int j = g * 128 + c;
  float val;
  if (k < 128)      val = (blk == 3) ? 0.f : M1[j * 128 + k];
  else if (k < 256) val = (blk == 3) ? 0.f : M2[j * 128 + (k - 128)];
  else              val = (blk == 2) ? 0.f : w_hh[(size_t)j * 128 + (k - 256)];
  unsigned short h = f2bf(val);
  Wh[idx] = h;
  Wl[idx] = f2bf(val - bf2f(h));
  if (k == 0) {
    float ccv, a1, a2;
    if (blk == 0)      { ccv = c0[c] + b_hh[c];             a1 = u1[c];       a2 = u2[c]; }
    else if (blk == 1) { ccv = c0[128 + c] + b_hh[128 + c]; a1 = u1[128 + c]; a2 = u2[128 + c]; }
    else if (blk == 2) { ccv = c0[256 + c];                 a1 = u1[256 + c]; a2 = u2[256 + c]; }
    else               { ccv = b_hh[256 + c];               a1 = 0.f;         a2 = 0.f; }
    cc[jp] = ccv; u1v[jp] = a1; u2v[jp] = a2;
  }
}

// ---------------- K1: emb gather -> Z_hi hidden cols + transposed bf16 HT -----
__global__ __launch_bounds__(256) void k1_gather(
    const int* __restrict__ x, const float* __restrict__ emb,
    unsigned short* __restrict__ hT, unsigned short* __restrict__ Z_hi) {
  __shared__ float hid[32][132];
  const int t = threadIdx.x;
  const int b = blockIdx.x;
  const int m0 = blockIdx.y * 32;
  for (int i = t; i < 32 * 128; i += 256) {
    int r = i >> 7, c = i & 127;
    int m = m0 + r;
    int rowc = b * 200 + (m < 200 ? m : 199);
    float h = emb[(size_t)x[rowc] * 128 + c];
    hid[r][c] = h;
    if (m < 200) Z_hi[(size_t)(b * 200 + m) * 384 + 256 + c] = f2bf(h);
  }
  __syncthreads();
  {
    int c = t >> 1, half = t & 1;
    bf16x8 p0, p1;
    #pragma unroll
    for (int j = 0; j < 16; ++j) {
      int ml = half * 16 + j;
      bool valid = (m0 + ml) < 200;
      float fv = valid ? hid[ml][c] : 0.f;
      if (j < 8) p0[j] = (short)f2bf(fv);
      else       p1[j - 8] = (short)f2bf(fv);
    }
    size_t base = ((size_t)(b * 128 + c)) * 224 + m0 + half * 16;
    *(bf16x8*)&hT[base]     = p0;
    *(bf16x8*)&hT[base + 8] = p1;
  }
}

// ---------------- K2: P = A @ H via MFMA, pipelined (counted vmcnt) -----------
// Bv staged via GLL with XOR-swizzled SOURCE slot (rule #21): LDS slot (r,s)
// holds logical slot s^((r>>1)&3); reads use the same XOR -> 2-way (free).
__global__ __launch_bounds__(256, 2) void k2_amm(
    const float* __restrict__ A, const unsigned short* __restrict__ hT,
    unsigned short* __restrict__ Z_hi, unsigned short* __restrict__ Z_lo,
    float* __restrict__ rs_in, float* __restrict__ rs_out) {
  __shared__ alignas(16) unsigned short Ainh[2][64][40];   // padded rows: 80B
  __shared__ alignas(16) unsigned short Ainl[2][64][40];
  __shared__ alignas(16) unsigned short Aouth[2][64][40];
  __shared__ alignas(16) unsigned short Aoutl[2][64][40];
  __shared__ alignas(16) unsigned short Bv[2][128][32];    // linear (GLL dest)
  const int t = threadIdx.x;
  const int b = blockIdx.x;
  const int m0 = blockIdx.y * 64;
  const int wv = t >> 6, lane = t & 63;
  const int q = lane & 15, quad = lane >> 4;
  const int sel = wv >> 1, nh2 = wv & 1;
  const int lrow = lane >> 2, lseg = lane & 3;
  const int sx8 = (lseg ^ ((lrow >> 1) & 3)) * 8;   // swizzled source slot (elems)
  const int qs8 = (quad ^ ((q >> 1) & 3)) * 8;      // swizzled read slot (elems)

  // per-thread A-load geometry: row am (0..63), seg aseg (0..3)
  const int am = t >> 2, aseg = t & 3;
  const int gm = m0 + am;
  const bool mvalid = gm < 200;
  const float* arow = A + (size_t)(b * 200 + (mvalid ? gm : 199)) * 400;

  f32x4 acc[4][4];
  #pragma unroll
  for (int i = 0; i < 4; ++i)
    #pragma unroll
    for (int j = 0; j < 4; ++j) acc[i][j] = 0.f;
  float rsi = 0.f, rso = 0.f;

  #define AISSUE(K0, P0, P1, Q0, Q1) do {                                       \
    int kb_ = (K0) + aseg * 8;                                                  \
    int kc_ = (kb_ < 200) ? kb_ : 0;                                            \
    P0 = *(const f32x4*)(arow + kc_);                                           \
    P1 = *(const f32x4*)(arow + kc_ + 4);                                       \
    Q0 = *(const f32x4*)(arow + 200 + kc_);                                     \
    Q1 = *(const f32x4*)(arow + 200 + kc_ + 4);                                 \
  } while (0)

  #define STAGE_B(K0, BUF) do {                                                 \
    _Pragma("unroll")                                                           \
    for (int op_ = 0; op_ < 2; ++op_) {                                         \
      int j_ = wv * 32 + op_ * 16 + lrow;                                       \
      int c_ = ((j_ >> 6) << 6) + ((j_ & 15) << 2) + ((j_ >> 4) & 3);           \
      GLL(hT + ((size_t)(b * 128 + c_)) * 224 + (K0) + sx8,                     \
          &Bv[BUF][wv * 32 + op_ * 16][0]);                                     \
    }                                                                           \
  } while (0)

  #define ACONV(K0, BUF, P0, P1, Q0, Q1) do {                                   \
    bool kv_ = mvalid && ((K0) + aseg * 8 < 200);                               \
    float fin_[8], fot_[8];                                                     \
    fin_[0]=P0.x; fin_[1]=P0.y; fin_[2]=P0.z; fin_[3]=P0.w;                     \
    fin_[4]=P1.x; fin_[5]=P1.y; fin_[6]=P1.z; fin_[7]=P1.w;                     \
    fot_[0]=Q0.x; fot_[1]=Q0.y; fot_[2]=Q0.z; fot_[3]=Q0.w;                     \
    fot_[4]=Q1.x; fot_[5]=Q1.y; fot_[6]=Q1.z; fot_[7]=Q1.w;                     \
    bf16x8 ih_, il_, oh_, ol_;                                                  \
    _Pragma("unroll")                                                           \
    for (int e_ = 0; e_ < 8; ++e_) {                                            \
      float fi_ = kv_ ? fin_[e_] : 0.f;                                         \
      float fo_ = kv_ ? fot_[e_] : 0.f;                                         \
      rsi += fi_; rso += fo_;                                                   \
      unsigned short h1_ = f2bf(fi_);                                           \
      ih_[e_] = (short)h1_; il_[e_] = (short)f2bf(fi_ - bf2f(h1_));             \
      unsigned short h2_ = f2bf(fo_);                                           \
      oh_[e_] = (short)h2_; ol_[e_] = (short)f2bf(fo_ - bf2f(h2_));             \
    }                                                                           \
    *(bf16x8*)&Ainh[BUF][am][aseg * 8]  = ih_;                                  \
    *(bf16x8*)&Ainl[BUF][am][aseg * 8]  = il_;                                  \
    *(bf16x8*)&Aouth[BUF][am][aseg * 8] = oh_;                                  \
    *(bf16x8*)&Aoutl[BUF][am][aseg * 8] = ol_;                                  \
  } while (0)

  #define K2COMP(BUF) do {                                                      \
    const unsigned short (*Ath_)[40] = sel ? Aouth[BUF] : Ainh[BUF];            \
    const unsigned short (*Atl_)[40] = sel ? Aoutl[BUF] : Ainl[BUF];            \
    bf16x8 ah_[4], al_[4];                                                      \
    _Pragma("unroll")                                                           \
    for (int mt = 0; mt < 4; ++mt) {                                            \
      ah_[mt] = *(const bf16x8*)&Ath_[mt * 16 + q][quad * 8];                   \
      al_[mt] = *(const bf16x8*)&Atl_[mt * 16 + q][quad * 8];                   \
    }                                                                           \
    _Pragma("unroll")                                                           \
    for (int nt = 0; nt < 4; ++nt) {                                            \
      bf16x8 bb_ = *(const bf16x8*)&Bv[BUF][nh2 * 64 + nt * 16 + q][qs8];       \
      _Pragma("unroll")                                                         \
      for (int mt = 0; mt < 4; ++mt) {                                          \
        acc[mt][nt] = MFMA16(ah_[mt], bb_, acc[mt][nt]);                        \
        acc[mt][nt] = MFMA16(al_[mt], bb_, acc[mt][nt]);                        \
      }                                                                         \
    }                                                                           \
  } while (0)

  // prologue: chunk 0 in flight
  f32x4 cp0, cp1, cq0, cq1;
  AISSUE(0, cp0, cp1, cq0, cq1);
  STAGE_B(0, 0);
  int buf = 0;

  for (int k = 0; k < 6; ++k) {
    const int k0n = (k + 1) * 32;
    f32x4 np0, np1, nq0, nq1;
    AISSUE(k0n, np0, np1, nq0, nq1);
    STAGE_B(k0n, buf ^ 1);
    KWAITV("6"); KSBAR();                 // A(k),B(k) drained; 6 newer in flight
    ACONV(k * 32, buf, cp0, cp1, cq0, cq1);
    KWAITL(); KSBAR(); KBAR();
    K2COMP(buf);
    KBAR();                               // protect Bv[buf] before next GLL
    cp0 = np0; cp1 = np1; cq0 = nq0; cq1 = nq1;
    buf ^= 1;
  }
  // tail: k = 6
  KWAITV("0"); KSBAR();
  ACONV(192, buf, cp0, cp1, cq0, cq1);
  KWAITL(); KSBAR(); KBAR();
  K2COMP(buf);

  // epilogue: coalesced ushort4 stores (4 consecutive columns per lane)
  const int colb = sel * 128 + nh2 * 64 + q * 4;
  #pragma unroll
  for (int mt = 0; mt < 4; ++mt) {
    #pragma unroll
    for (int r = 0; r < 4; ++r) {
      int m = m0 + mt * 16 + quad * 4 + r;
      if (m < 200) {
        u16x4 h4, l4;
        #pragma unroll
        for (int nt = 0; nt < 4; ++nt) {
          float v = acc[mt][nt][r];
          unsigned short hs = f2bf(v);
          h4[nt] = hs;
          l4[nt] = f2bf(v - bf2f(hs));
        }
        size_t row = (size_t)(b * 200 + m);
        *(u16x4*)&Z_hi[row * 384 + colb] = h4;
        *(u16x4*)&Z_lo[row * 256 + colb] = l4;
      }
    }
  }
  // reduce row sums across the 4 seg-lanes of each row, store once
  rsi += __shfl_xor(rsi, 1); rsi += __shfl_xor(rsi, 2);
  rso += __shfl_xor(rso, 1); rso += __shfl_xor(rso, 2);
  if (aseg == 0 && mvalid) {
    rs_in[(size_t)b * 200 + gm]  = rsi;
    rs_out[(size_t)b * 200 + gm] = rso;
  }
  #undef AISSUE
  #undef STAGE_B
  #undef ACONV
  #undef K2COMP
}

// ---------------- K3: global_load_lds pipelined GEMM + gates ------------------
// All LDS tiles staged via GLL with XOR-swizzled SOURCE slot, read with the
// same XOR (rule #21) -> fragment ds_reads go 8-way-conflicted -> 2-way (free).
__global__ __launch_bounds__(256, 2) void k3_gates(
    const unsigned short* __restrict__ Z_hi, const unsigned short* __restrict__ Z_lo,
    const unsigned short* __restrict__ Wh, const unsigned short* __restrict__ Wl,
    const float* __restrict__ cc, const float* __restrict__ u1v,
    const float* __restrict__ u2v, const float* __restrict__ rs_in,
    const float* __restrict__ rs_out, float* __restrict__ out) {
  __shared__ alignas(16) unsigned short WhS[256][32];      // 16 KB (per-kc slice)
  __shared__ alignas(16) unsigned short WlS[256][32];      // 16 KB
  __shared__ alignas(16) unsigned short Ah[2][128][32];    // 16 KB (dbuf)
  __shared__ alignas(16) unsigned short Al[2][128][32];    // 16 KB (dbuf)
  const int t = threadIdx.x;
  const int w = t >> 6, lane = t & 63;
  const int q = lane & 15, quad = lane >> 4;
  const int mh = w >> 1, ng = w & 1;
  const int lrow = lane >> 2, lseg = lane & 3;
  const int sx8 = (lseg ^ ((lrow >> 1) & 3)) * 8;   // swizzled source slot
  const int qs8 = (quad ^ ((q >> 1) & 3)) * 8;      // swizzled read slot
  const size_t rbase = (size_t)blockIdx.x * 128;
  const int nh = blockIdx.y;

  f32x4 acc[4][8];
  #pragma unroll
  for (int i = 0; i < 4; ++i)
    #pragma unroll
    for (int j = 0; j < 8; ++j) acc[i][j] = 0.f;

  #define STAGE_W(KC) do {                                                      \
    const int k0_ = (KC) * 32;                                                  \
    _Pragma("unroll")                                                           \
    for (int c_ = 0; c_ < 4; ++c_) {                                            \
      int j_ = w * 64 + c_ * 16;                                                \
      GLL(Wh + (size_t)(nh * 256 + j_ + lrow) * 384 + k0_ + sx8,                \
          &WhS[j_][0]);                                                         \
    }                                                                           \
    _Pragma("unroll")                                                           \
    for (int c_ = 0; c_ < 4; ++c_) {                                            \
      int j_ = w * 64 + c_ * 16;                                                \
      GLL(Wl + (size_t)(nh * 256 + j_ + lrow) * 384 + k0_ + sx8,                \
          &WlS[j_][0]);                                                         \
    }                                                                           \
  } while (0)

  #define STAGE_A1(KC, BUF) do {                                                \
    const int k0_ = (KC) * 32;                                                  \
    _Pragma("unroll")                                                           \
    for (int c_ = 0; c_ < 2; ++c_) {                                            \
      int m_ = w * 32 + c_ * 16;                                                \
      GLL(Z_hi + (rbase + m_ + lrow) * 384 + k0_ + sx8, &Ah[BUF][m_][0]);       \
    }                                                                           \
    _Pragma("unroll")                                                           \
    for (int c_ = 0; c_ < 2; ++c_) {                                            \
      int m_ = w * 32 + c_ * 16;                                                \
      GLL(Z_lo + (rbase + m_ + lrow) * 256 + k0_ + sx8, &Al[BUF][m_][0]);       \
    }                                                                           \
  } while (0)

  #define STAGE_A2(KC, BUF) do {                                                \
    const int k0_ = (KC) * 32;                                                  \
    _Pragma("unroll")                                                           \
    for (int c_ = 0; c_ < 2; ++c_) {                                            \
      int m_ = w * 32 + c_ * 16;                                                \
      GLL(Z_hi + (rbase + m_ + lrow) * 384 + k0_ + sx8, &Ah[BUF][m_][0]);       \
    }                                                                           \
  } while (0)

  #define COMPUTE1(BUF) do {                                                    \
    bf16x8 ah_[4], al_[4];                                                      \
    _Pragma("unroll")                                                           \
    for (int mt = 0; mt < 4; ++mt) {                                            \
      ah_[mt] = *(const bf16x8*)&Ah[BUF][mh * 64 + mt * 16 + q][qs8];           \
      al_[mt] = *(const bf16x8*)&Al[BUF][mh * 64 + mt * 16 + q][qs8];           \
    }                                                                           \
    _Pragma("unroll")                                                           \
    for (int tt = 0; tt < 6; ++tt) {                                            \
      bf16x8 bh = *(const bf16x8*)&WhS[ng * 128 + tt * 16 + q][qs8];            \
      bf16x8 bl = *(const bf16x8*)&WlS[ng * 128 + tt * 16 + q][qs8];            \
      _Pragma("unroll")                                                         \
      for (int mt = 0; mt < 4; ++mt) {                                          \
        acc[mt][tt] = MFMA16(ah_[mt], bh, acc[mt][tt]);                         \
        acc[mt][tt] = MFMA16(ah_[mt], bl, acc[mt][tt]);                         \
        acc[mt][tt] = MFMA16(al_[mt], bh, acc[mt][tt]);                         \
      }                                                                         \
    }                                                                           \
  } while (0)

  #define COMPUTE2(BUF) do {                                                    \
    bf16x8 ah_[4];                                                              \
    _Pragma("unroll")                                                           \
    for (int mt = 0; mt < 4; ++mt)                                              \
      ah_[mt] = *(const bf16x8*)&Ah[BUF][mh * 64 + mt * 16 + q][qs8];           \
    _Pragma("unroll")                                                           \
    for (int ti = 0; ti < 6; ++ti) {                                            \
      const int tt = (ti < 4) ? ti : ti + 2;  /* tiles 0,1,2,3,6,7 */           \
      bf16x8 bh = *(const bf16x8*)&WhS[ng * 128 + tt * 16 + q][qs8];            \
      bf16x8 bl = *(const bf16x8*)&WlS[ng * 128 + tt * 16 + q][qs8];            \
      _Pragma("unroll")                                                         \
      for (int mt = 0; mt < 4; ++mt) {                                          \
        acc[mt][tt] = MFMA16(ah_[mt], bh, acc[mt][tt]);                         \
        acc[mt][tt] = MFMA16(ah_[mt], bl, acc[mt][tt]);                         \
      }                                                                         \
    }                                                                           \
  } while (0)

  // prologue: stage A(0)
  STAGE_A1(0, 0);
  int buf = 0;
  // ---- phase 1: kc 0..6 — A-next has 4 ops -> vmcnt(4)
  #pragma unroll
  for (int kc = 0; kc < 7; ++kc) {
    STAGE_W(kc);
    STAGE_A1(kc + 1, buf ^ 1);
    KWAITV("4"); KSBAR(); KBAR();
    COMPUTE1(buf);
    KWAITL(); KSBAR(); KBAR();
    buf ^= 1;
  }
  // ---- kc = 7: next stage is phase-2 style (2 ops) -> vmcnt(2)
  {
    STAGE_W(7);
    STAGE_A2(8, buf ^ 1);
    KWAITV("2"); KSBAR(); KBAR();
    COMPUTE1(buf);
    KWAITL(); KSBAR(); KBAR();
    buf ^= 1;
  }
  // ---- phase 2: kc 8..10 — A-next 2 ops -> vmcnt(2)
  #pragma unroll
  for (int kc = 8; kc < 11; ++kc) {
    STAGE_W(kc);
    STAGE_A2(kc + 1, buf ^ 1);
    KWAITV("2"); KSBAR(); KBAR();
    COMPUTE2(buf);
    KWAITL(); KSBAR(); KBAR();
    buf ^= 1;
  }
  // ---- kc = 11: nothing to prefetch -> vmcnt(0)
  {
    STAGE_W(11);
    KWAITV("0"); KSBAR(); KBAR();
    COMPUTE2(buf);
  }

  // gates epilogue with folded rank-1 biases
  const int jb = nh * 256 + ng * 128;
  float cs[2][4], a1s[2][3], a2s[2][3];
  #pragma unroll
  for (int s = 0; s < 2; ++s) {
    #pragma unroll
    for (int gb = 0; gb < 4; ++gb) cs[s][gb] = cc[jb + (gb * 2 + s) * 16 + q];
    #pragma unroll
    for (int gb = 0; gb < 3; ++gb) {
      a1s[s][gb] = u1v[jb + (gb * 2 + s) * 16 + q];
      a2s[s][gb] = u2v[jb + (gb * 2 + s) * 16 + q];
    }
  }
  #pragma unroll
  for (int mt = 0; mt < 4; ++mt) {
    #pragma unroll
    for (int r = 0; r < 4; ++r) {
      size_t row = rbase + mh * 64 + mt * 16 + quad * 4 + r;
      float rin = rs_in[row], rot = rs_out[row];
      #pragma unroll
      for (int s = 0; s < 2; ++s) {
        int c = nh * 64 + ng * 32 + s * 16 + q;
        float sr  = acc[mt][0 + s][r] + cs[s][0] + rin * a1s[s][0] + rot * a2s[s][0];
        float si  = acc[mt][2 + s][r] + cs[s][1] + rin * a1s[s][1] + rot * a2s[s][1];
        float ani = acc[mt][4 + s][r] + cs[s][2] + rin * a1s[s][2] + rot * a2s[s][2];
        float anh = acc[mt][6 + s][r] + cs[s][3];
        float g_rs = fsigmoid(sr);
        float g_in = fsigmoid(si);
        float g_ot = ftanh(ani + g_rs * anh);
        float h = bf2f(Z_hi[row * 384 + 256 + c]);
        out[row * 128 + c] = g_ot + g_in * (h - g_ot);
      }
    }
  }
  #undef STAGE_W
  #undef STAGE_A1
  #undef STAGE_A2
  #undef COMPUTE1
  #undef COMPUTE2
}

extern "C" void kernel_launch(void* const* d_in, const int* in_sizes, int n_in,
                              void* d_out, int out_size, void* d_ws, size_t ws_size,
                              hipStream_t stream) {
  const int*   x     = (const int*)d_in[0];
  const float* A     = (const float*)d_in[1];
  const float* emb   = (const float*)d_in[2];
  const float* w_in  = (const float*)d_in[3];
  const float* b_in  = (const float*)d_in[4];
  const float* w_out = (const float*)d_in[5];
  const float* b_out = (const float*)d_in[6];
  const float* w_ih  = (const float*)d_in[7];
  const float* b_ih  = (const float*)d_in[8];
  const float* w_hh  = (const float*)d_in[9];
  const float* b_hh  = (const float*)d_in[10];
  const float* b_iah = (const float*)d_in[11];
  const float* b_oah = (const float*)d_in[12];
  float* out = (float*)d_out;
  char* ws = (char*)d_ws;

  if (ws_size < WS_BYTES) return;

  unsigned short* Z_hi = (unsigned short*)(ws + OFF_ZHI);
  unsigned short* Z_lo = (unsigned short*)(ws + OFF_ZLO);
  unsigned short* hT   = (unsigned short*)(ws + OFF_HT);
  float* M1 = (float*)(ws + OFF_M1);
  float* M2 = (float*)(ws + OFF_M2);
  unsigned short* Wh = (unsigned short*)(ws + OFF_WH);
  unsigned short* Wl = (unsigned short*)(ws + OFF_WL);
  float* ccv = (float*)(ws + OFF_CC);
  float* u1v = (float*)(ws + OFF_U1V);
  float* u2v = (float*)(ws + OFF_U2V);
  float* u1  = (float*)(ws + OFF_U1);
  float* u2  = (float*)(ws + OFF_U2);
  float* c0  = (float*)(ws + OFF_C0);
  float* rs_in  = (float*)(ws + OFF_RSI);
  float* rs_out = (float*)(ws + OFF_RSO);

  kprep<<<384, 128, 0, stream>>>(w_ih, w_in, w_out, b_in, b_out, b_iah, b_oah,
                                 b_ih, M1, M2, u1, u2, c0);
  wcat_build<<<(512 * 384 + 255) / 256, 256, 0, stream>>>(M1, M2, w_hh, b_hh,
                                                          u1, u2, c0, Wh, Wl,
                                                          ccv, u1v, u2v);
  dim3 g1(BB, 7);
  k1_gather<<<g1, 256, 0, stream>>>(x, emb, hT, Z_hi);
  dim3 g2(BB, 4);
  k2_amm<<<g2, 256, 0, stream>>>(A, hT, Z_hi, Z_lo, rs_in, rs_out);
  dim3 g3(BNROWS / 128, 2);
  k3_gates<<<g3, 256, 0, stream>>>(Z_hi, Z_lo, Wh, Wl, ccv, u1v, u2v,
                                   rs_in, rs_out, out);
}

// Round 7
// 495.853 us; speedup vs baseline: 1.0171x; 1.0171x over previous
//
#include <hip/hip_runtime.h>
#include <math.h>

#define BB 512
#define NN 200
#define DD 128
#define BNROWS (BB*NN)   // 102400

typedef float f32x4 __attribute__((ext_vector_type(4)));
typedef short bf16x8 __attribute__((ext_vector_type(8)));
typedef unsigned short u16x4 __attribute__((ext_vector_type(4)));

#define MFMA16(a,b,c) __builtin_amdgcn_mfma_f32_16x16x32_bf16(a,b,c,0,0,0)

// async global -> LDS, 16B per lane. LDS dest is WAVE-UNIFORM base; HW adds lane*16.
#define GLL(gp, lp) __builtin_amdgcn_global_load_lds( \
    (const __attribute__((address_space(1))) unsigned int*)(gp), \
    (__attribute__((address_space(3))) unsigned int*)(lp), 16, 0, 0)

#define KWAITV(S) asm volatile("s_waitcnt vmcnt(" S ")" ::: "memory")
#define KWAITL()  asm volatile("s_waitcnt lgkmcnt(0)" ::: "memory")
#define KBAR()    __builtin_amdgcn_s_barrier()
#define KSBAR()   __builtin_amdgcn_sched_barrier(0)

// ---------------- workspace layout (bytes) ----------------
#define OFF_ZHI   ((size_t)0)
#define OFF_ZLO   (OFF_ZHI + (size_t)BNROWS*384*2)
#define OFF_HT    (OFF_ZLO + (size_t)BNROWS*256*2)
#define OFF_M1    (OFF_HT  + (size_t)BB*128*224*2)
#define OFF_M2    (OFF_M1  + (size_t)384*128*4)
#define OFF_WH    (OFF_M2  + (size_t)384*128*4)
#define OFF_WL    (OFF_WH  + (size_t)512*384*2)
#define OFF_CC    (OFF_WL  + (size_t)512*384*2)
#define OFF_U1V   (OFF_CC  + 512*4)
#define OFF_U2V   (OFF_U1V + 512*4)
#define OFF_U1    (OFF_U2V + 512*4)
#define OFF_U2    (OFF_U1  + 384*4)
#define OFF_C0    (OFF_U2  + 384*4)
#define OFF_RSI   (OFF_C0  + 384*4)
#define OFF_RSO   (OFF_RSI + (size_t)BNROWS*4)
#define WS_BYTES  (OFF_RSO + (size_t)BNROWS*4)

__device__ inline unsigned short f2bf(float x) {
  unsigned int u = __float_as_uint(x);
  unsigned int r = u + 0x7FFFu + ((u >> 16) & 1u);   // RNE
  return (unsigned short)(r >> 16);
}
__device__ inline float bf2f(unsigned short h) {
  return __uint_as_float(((unsigned int)h) << 16);
}
__device__ inline float fsigmoid(float x) {
  return 1.f / (1.f + __expf(-x));
}
__device__ inline float ftanh(float x) {
  x = fminf(15.f, fmaxf(-15.f, x));   // avoid inf/inf
  float e = __expf(-2.f * x);
  return (1.f - e) / (1.f + e);
}

// ---------------- kprep: M1 = W1 @ w_in, M2 = W2 @ w_out; u1,u2,c0 vectors ----
__global__ __launch_bounds__(128) void kprep(
    const float* __restrict__ w_ih, const float* __restrict__ w_in,
    const float* __restrict__ w_out, const float* __restrict__ b_in,
    const float* __restrict__ b_out, const float* __restrict__ b_iah,
    const float* __restrict__ b_oah, const float* __restrict__ b_ih,
    float* __restrict__ M1, float* __restrict__ M2,
    float* __restrict__ u1, float* __restrict__ u2, float* __restrict__ c0) {
  __shared__ float wrow[256];
  const int j = blockIdx.x;        // 0..383
  const int k = threadIdx.x;       // 0..127
  wrow[k]       = w_ih[(size_t)j * 256 + k];
  wrow[128 + k] = w_ih[(size_t)j * 256 + 128 + k];
  __syncthreads();
  float a1 = 0.f, a2 = 0.f;
  for (int t = 0; t < 128; ++t) {
    a1 = fmaf(wrow[t],       w_in[t * 128 + k],  a1);
    a2 = fmaf(wrow[128 + t], w_out[t * 128 + k], a2);
  }
  M1[j * 128 + k] = a1;
  M2[j * 128 + k] = a2;
  if (k == 0) {
    float s1 = 0.f, s2 = 0.f, s0 = 0.f;
    for (int t = 0; t < 128; ++t) {
      s1 = fmaf(wrow[t], b_in[t], s1);
      s2 = fmaf(wrow[128 + t], b_out[t], s2);
      s0 = fmaf(wrow[t], b_iah[t], s0);
      s0 = fmaf(wrow[128 + t], b_oah[t], s0);
    }
    u1[j] = s1; u2[j] = s2; c0[j] = s0 + b_ih[j];
  }
}

// ---------------- Wcat build: permuted 512-col [r | i | n_P | n_h], K=384 ------
__global__ void wcat_build(const float* __restrict__ M1, const float* __restrict__ M2,
                           const float* __restrict__ w_hh, const float* __restrict__ b_hh,
                           const float* __restrict__ u1, const float* __restrict__ u2,
                           const float* __restrict__ c0,
                           unsigned short* __restrict__ Wh, unsigned short* __restrict__ Wl,
                           float* __restrict__ cc, float* __restrict__ u1v,
                           float* __restrict__ u2v) {
  int idx = blockIdx.x * 256 + threadIdx.x;   // 512*384
  if (idx >= 512 * 384) return;
  int jp = idx / 384, k = idx - jp * 384;
  int nh = jp >> 8, ng = (jp >> 7) & 1, t = (jp >> 4) & 7, q = jp & 15;
  int blk = t >> 1, s = t & 1;
  int c = nh * 64 + ng * 32 + s * 16 + q;
  int g = (blk <= 1) ? blk : 2;
  int j = g * 128 + c;
  float val;
  if (k < 128)      val = (blk == 3) ? 0.f : M1[j * 128 + k];
  else if (k < 256) val = (blk == 3) ? 0.f : M2[j * 128 + (k - 128)];
  else              val = (blk == 2) ? 0.f : w_hh[(size_t)j * 128 + (k - 256)];
  unsigned short h = f2bf(val);
  Wh[idx] = h;
  Wl[idx] = f2bf(val - bf2f(h));
  if (k == 0) {
    float ccv, a1, a2;
    if (blk == 0)      { ccv = c0[c] + b_hh[c];             a1 = u1[c];       a2 = u2[c]; }
    else if (blk == 1) { ccv = c0[128 + c] + b_hh[128 + c]; a1 = u1[128 + c]; a2 = u2[128 + c]; }
    else if (blk == 2) { ccv = c0[256 + c];                 a1 = u1[256 + c]; a2 = u2[256 + c]; }
    else               { ccv = b_hh[256 + c];               a1 = 0.f;         a2 = 0.f; }
    cc[jp] = ccv; u1v[jp] = a1; u2v[jp] = a2;
  }
}

// ---------------- K1: emb gather -> Z_hi hidden cols + transposed bf16 HT -----
__global__ __launch_bounds__(256) void k1_gather(
    const int* __restrict__ x, const float* __restrict__ emb,
    unsigned short* __restrict__ hT, unsigned short* __restrict__ Z_hi) {
  __shared__ float hid[32][132];
  const int t = threadIdx.x;
  const int b = blockIdx.x;
  const int m0 = blockIdx.y * 32;
  for (int i = t; i < 32 * 128; i += 256) {
    int r = i >> 7, c = i & 127;
    int m = m0 + r;
    int rowc = b * 200 + (m < 200 ? m : 199);
    float h = emb[(size_t)x[rowc] * 128 + c];
    hid[r][c] = h;
    if (m < 200) Z_hi[(size_t)(b * 200 + m) * 384 + 256 + c] = f2bf(h);
  }
  __syncthreads();
  {
    int c = t >> 1, half = t & 1;
    bf16x8 p0, p1;
    #pragma unroll
    for (int j = 0; j < 16; ++j) {
      int ml = half * 16 + j;
      bool valid = (m0 + ml) < 200;
      float fv = valid ? hid[ml][c] : 0.f;
      if (j < 8) p0[j] = (short)f2bf(fv);
      else       p1[j - 8] = (short)f2bf(fv);
    }
    size_t base = ((size_t)(b * 128 + c)) * 224 + m0 + half * 16;
    *(bf16x8*)&hT[base]     = p0;
    *(bf16x8*)&hT[base + 8] = p1;
  }
}

// ---------------- K2: P = A @ H via MFMA, pipelined (counted vmcnt) -----------
// Bv staged via GLL with XOR-swizzled SOURCE slot (rule #21): LDS slot (r,s)
// holds logical slot s^((r>>1)&3); reads use the same XOR -> 2-way (free).
// (r6 A/B: this swizzle HELPED k2 by ~33us — its Bv conflict was critical-path.)
__global__ __launch_bounds__(256, 2) void k2_amm(
    const float* __restrict__ A, const unsigned short* __restrict__ hT,
    unsigned short* __restrict__ Z_hi, unsigned short* __restrict__ Z_lo,
    float* __restrict__ rs_in, float* __restrict__ rs_out) {
  __shared__ alignas(16) unsigned short Ainh[2][64][40];   // padded rows: 80B
  __shared__ alignas(16) unsigned short Ainl[2][64][40];
  __shared__ alignas(16) unsigned short Aouth[2][64][40];
  __shared__ alignas(16) unsigned short Aoutl[2][64][40];
  __shared__ alignas(16) unsigned short Bv[2][128][32];    // linear (GLL dest)
  const int t = threadIdx.x;
  const int b = blockIdx.x;
  const int m0 = blockIdx.y * 64;
  const int wv = t >> 6, lane = t & 63;
  const int q = lane & 15, quad = lane >> 4;
  const int sel = wv >> 1, nh2 = wv & 1;
  const int lrow = lane >> 2, lseg = lane & 3;
  const int sx8 = (lseg ^ ((lrow >> 1) & 3)) * 8;   // swizzled source slot (elems)
  const int qs8 = (quad ^ ((q >> 1) & 3)) * 8;      // swizzled read slot (elems)

  // per-thread A-load geometry: row am (0..63), seg aseg (0..3)
  const int am = t >> 2, aseg = t & 3;
  const int gm = m0 + am;
  const bool mvalid = gm < 200;
  const float* arow = A + (size_t)(b * 200 + (mvalid ? gm : 199)) * 400;

  f32x4 acc[4][4];
  #pragma unroll
  for (int i = 0; i < 4; ++i)
    #pragma unroll
    for (int j = 0; j < 4; ++j) acc[i][j] = 0.f;
  float rsi = 0.f, rso = 0.f;

  #define AISSUE(K0, P0, P1, Q0, Q1) do {                                       \
    int kb_ = (K0) + aseg * 8;                                                  \
    int kc_ = (kb_ < 200) ? kb_ : 0;                                            \
    P0 = *(const f32x4*)(arow + kc_);                                           \
    P1 = *(const f32x4*)(arow + kc_ + 4);                                       \
    Q0 = *(const f32x4*)(arow + 200 + kc_);                                     \
    Q1 = *(const f32x4*)(arow + 200 + kc_ + 4);                                 \
  } while (0)

  #define STAGE_B(K0, BUF) do {                                                 \
    _Pragma("unroll")                                                           \
    for (int op_ = 0; op_ < 2; ++op_) {                                         \
      int j_ = wv * 32 + op_ * 16 + lrow;                                       \
      int c_ = ((j_ >> 6) << 6) + ((j_ & 15) << 2) + ((j_ >> 4) & 3);           \
      GLL(hT + ((size_t)(b * 128 + c_)) * 224 + (K0) + sx8,                     \
          &Bv[BUF][wv * 32 + op_ * 16][0]);                                     \
    }                                                                           \
  } while (0)

  #define ACONV(K0, BUF, P0, P1, Q0, Q1) do {                                   \
    bool kv_ = mvalid && ((K0) + aseg * 8 < 200);                               \
    float fin_[8], fot_[8];                                                     \
    fin_[0]=P0.x; fin_[1]=P0.y; fin_[2]=P0.z; fin_[3]=P0.w;                     \
    fin_[4]=P1.x; fin_[5]=P1.y; fin_[6]=P1.z; fin_[7]=P1.w;                     \
    fot_[0]=Q0.x; fot_[1]=Q0.y; fot_[2]=Q0.z; fot_[3]=Q0.w;                     \
    fot_[4]=Q1.x; fot_[5]=Q1.y; fot_[6]=Q1.z; fot_[7]=Q1.w;                     \
    bf16x8 ih_, il_, oh_, ol_;                                                  \
    _Pragma("unroll")                                                           \
    for (int e_ = 0; e_ < 8; ++e_) {                                            \
      float fi_ = kv_ ? fin_[e_] : 0.f;                                         \
      float fo_ = kv_ ? fot_[e_] : 0.f;                                         \
      rsi += fi_; rso += fo_;                                                   \
      unsigned short h1_ = f2bf(fi_);                                           \
      ih_[e_] = (short)h1_; il_[e_] = (short)f2bf(fi_ - bf2f(h1_));             \
      unsigned short h2_ = f2bf(fo_);                                           \
      oh_[e_] = (short)h2_; ol_[e_] = (short)f2bf(fo_ - bf2f(h2_));             \
    }                                                                           \
    *(bf16x8*)&Ainh[BUF][am][aseg * 8]  = ih_;                                  \
    *(bf16x8*)&Ainl[BUF][am][aseg * 8]  = il_;                                  \
    *(bf16x8*)&Aouth[BUF][am][aseg * 8] = oh_;                                  \
    *(bf16x8*)&Aoutl[BUF][am][aseg * 8] = ol_;                                  \
  } while (0)

  #define K2COMP(BUF) do {                                                      \
    const unsigned short (*Ath_)[40] = sel ? Aouth[BUF] : Ainh[BUF];            \
    const unsigned short (*Atl_)[40] = sel ? Aoutl[BUF] : Ainl[BUF];            \
    bf16x8 ah_[4], al_[4];                                                      \
    _Pragma("unroll")                                                           \
    for (int mt = 0; mt < 4; ++mt) {                                            \
      ah_[mt] = *(const bf16x8*)&Ath_[mt * 16 + q][quad * 8];                   \
      al_[mt] = *(const bf16x8*)&Atl_[mt * 16 + q][quad * 8];                   \
    }                                                                           \
    _Pragma("unroll")                                                           \
    for (int nt = 0; nt < 4; ++nt) {                                            \
      bf16x8 bb_ = *(const bf16x8*)&Bv[BUF][nh2 * 64 + nt * 16 + q][qs8];       \
      _Pragma("unroll")                                                         \
      for (int mt = 0; mt < 4; ++mt) {                                          \
        acc[mt][nt] = MFMA16(ah_[mt], bb_, acc[mt][nt]);                        \
        acc[mt][nt] = MFMA16(al_[mt], bb_, acc[mt][nt]);                        \
      }                                                                         \
    }                                                                           \
  } while (0)

  // prologue: chunk 0 in flight
  f32x4 cp0, cp1, cq0, cq1;
  AISSUE(0, cp0, cp1, cq0, cq1);
  STAGE_B(0, 0);
  int buf = 0;

  for (int k = 0; k < 6; ++k) {
    const int k0n = (k + 1) * 32;
    f32x4 np0, np1, nq0, nq1;
    AISSUE(k0n, np0, np1, nq0, nq1);
    STAGE_B(k0n, buf ^ 1);
    KWAITV("6"); KSBAR();                 // A(k),B(k) drained; 6 newer in flight
    ACONV(k * 32, buf, cp0, cp1, cq0, cq1);
    KWAITL(); KSBAR(); KBAR();
    K2COMP(buf);
    KBAR();                               // protect Bv[buf] before next GLL
    cp0 = np0; cp1 = np1; cq0 = nq0; cq1 = nq1;
    buf ^= 1;
  }
  // tail: k = 6
  KWAITV("0"); KSBAR();
  ACONV(192, buf, cp0, cp1, cq0, cq1);
  KWAITL(); KSBAR(); KBAR();
  K2COMP(buf);

  // epilogue: coalesced ushort4 stores (4 consecutive columns per lane)
  const int colb = sel * 128 + nh2 * 64 + q * 4;
  #pragma unroll
  for (int mt = 0; mt < 4; ++mt) {
    #pragma unroll
    for (int r = 0; r < 4; ++r) {
      int m = m0 + mt * 16 + quad * 4 + r;
      if (m < 200) {
        u16x4 h4, l4;
        #pragma unroll
        for (int nt = 0; nt < 4; ++nt) {
          float v = acc[mt][nt][r];
          unsigned short hs = f2bf(v);
          h4[nt] = hs;
          l4[nt] = f2bf(v - bf2f(hs));
        }
        size_t row = (size_t)(b * 200 + m);
        *(u16x4*)&Z_hi[row * 384 + colb] = h4;
        *(u16x4*)&Z_lo[row * 256 + colb] = l4;
      }
    }
  }
  // reduce row sums across the 4 seg-lanes of each row, store once
  rsi += __shfl_xor(rsi, 1); rsi += __shfl_xor(rsi, 2);
  rso += __shfl_xor(rso, 1); rso += __shfl_xor(rso, 2);
  if (aseg == 0 && mvalid) {
    rs_in[(size_t)b * 200 + gm]  = rsi;
    rs_out[(size_t)b * 200 + gm] = rso;
  }
  #undef AISSUE
  #undef STAGE_B
  #undef ACONV
  #undef K2COMP
}

// ---------------- K3: fully double-buffered GLL pipeline + gates --------------
// Depth-2 prefetch for BOTH W and A (W was issue-then-wait before — the stall).
// W staged COMPACTED to the 192 rows actually used per phase (of 256), so the
// double buffer fits: 2*(12+12)KB W + 32KB A = 80KB -> 2 blocks/CU exactly.
// Linear LDS slots (r6 showed source-swizzle costs more than the hidden 8-way
// ds_read conflict saves in this schedule).
__global__ __launch_bounds__(256, 2) void k3_gates(
    const unsigned short* __restrict__ Z_hi, const unsigned short* __restrict__ Z_lo,
    const unsigned short* __restrict__ Wh, const unsigned short* __restrict__ Wl,
    const float* __restrict__ cc, const float* __restrict__ u1v,
    const float* __restrict__ u2v, const float* __restrict__ rs_in,
    const float* __restrict__ rs_out, float* __restrict__ out) {
  __shared__ alignas(16) unsigned short WhS[2][192][32];   // 24 KB (dbuf, compact)
  __shared__ alignas(16) unsigned short WlS[2][192][32];   // 24 KB
  __shared__ alignas(16) unsigned short Ah[2][128][32];    // 16 KB (dbuf)
  __shared__ alignas(16) unsigned short Al[2][128][32];    // 16 KB (dbuf)
  const int t = threadIdx.x;
  const int w = t >> 6, lane = t & 63;
  const int q = lane & 15, quad = lane >> 4;
  const int mh = w >> 1, ng = w & 1;
  const int lrow = lane >> 2, lseg = lane & 3;
  const size_t rbase = (size_t)blockIdx.x * 128;
  const int nh = blockIdx.y;

  f32x4 acc[4][8];
  #pragma unroll
  for (int i = 0; i < 4; ++i)
    #pragma unroll
    for (int j = 0; j < 8; ++j) acc[i][j] = 0.f;

  // compact W layout: phase1 row j (0..191): hp=j/96, W row = nh*256+hp*128+(j-hp*96)
  #define STAGE_W1(KC, BUF) do {                                                \
    const int k0_ = (KC) * 32;                                                  \
    _Pragma("unroll")                                                           \
    for (int c_ = 0; c_ < 3; ++c_) {                                            \
      int j0_ = w * 48 + c_ * 16;                                               \
      int hp_ = (j0_ >= 96) ? 1 : 0;                                            \
      int gr_ = nh * 256 + hp_ * 128 + (j0_ - hp_ * 96) + lrow;                 \
      GLL(Wh + (size_t)gr_ * 384 + k0_ + lseg * 8, &WhS[BUF][j0_][0]);          \
    }                                                                           \
    _Pragma("unroll")                                                           \
    for (int c_ = 0; c_ < 3; ++c_) {                                            \
      int j0_ = w * 48 + c_ * 16;                                               \
      int hp_ = (j0_ >= 96) ? 1 : 0;                                            \
      int gr_ = nh * 256 + hp_ * 128 + (j0_ - hp_ * 96) + lrow;                 \
      GLL(Wl + (size_t)gr_ * 384 + k0_ + lseg * 8, &WlS[BUF][j0_][0]);          \
    }                                                                           \
  } while (0)

  // phase2: compact row j: hp=j/96, jc=j-hp*96; W row = nh*256+hp*128+(jc<64?jc:jc+32)
  #define STAGE_W2(KC, BUF) do {                                                \
    const int k0_ = (KC) * 32;                                                  \
    _Pragma("unroll")                                                           \
    for (int c_ = 0; c_ < 3; ++c_) {                                            \
      int j0_ = w * 48 + c_ * 16;                                               \
      int hp_ = (j0_ >= 96) ? 1 : 0;                                            \
      int jc_ = j0_ - hp_ * 96;                                                 \
      int gr_ = nh * 256 + hp_ * 128 + (jc_ < 64 ? jc_ : jc_ + 32) + lrow;      \
      GLL(Wh + (size_t)gr_ * 384 + k0_ + lseg * 8, &WhS[BUF][j0_][0]);          \
    }                                                                           \
    _Pragma("unroll")                                                           \
    for (int c_ = 0; c_ < 3; ++c_) {                                            \
      int j0_ = w * 48 + c_ * 16;                                               \
      int hp_ = (j0_ >= 96) ? 1 : 0;                                            \
      int jc_ = j0_ - hp_ * 96;                                                 \
      int gr_ = nh * 256 + hp_ * 128 + (jc_ < 64 ? jc_ : jc_ + 32) + lrow;      \
      GLL(Wl + (size_t)gr_ * 384 + k0_ + lseg * 8, &WlS[BUF][j0_][0]);          \
    }                                                                           \
  } while (0)

  #define STAGE_A1(KC, BUF) do {                                                \
    const int k0_ = (KC) * 32;                                                  \
    _Pragma("unroll")                                                           \
    for (int c_ = 0; c_ < 2; ++c_) {                                            \
      int m_ = w * 32 + c_ * 16;                                                \
      GLL(Z_hi + (rbase + m_ + lrow) * 384 + k0_ + lseg * 8, &Ah[BUF][m_][0]);  \
    }                                                                           \
    _Pragma("unroll")                                                           \
    for (int c_ = 0; c_ < 2; ++c_) {                                            \
      int m_ = w * 32 + c_ * 16;                                                \
      GLL(Z_lo + (rbase + m_ + lrow) * 256 + k0_ + lseg * 8, &Al[BUF][m_][0]);  \
    }                                                                           \
  } while (0)

  #define STAGE_A2(KC, BUF) do {                                                \
    const int k0_ = (KC) * 32;                                                  \
    _Pragma("unroll")                                                           \
    for (int c_ = 0; c_ < 2; ++c_) {                                            \
      int m_ = w * 32 + c_ * 16;                                                \
      GLL(Z_hi + (rbase + m_ + lrow) * 384 + k0_ + lseg * 8, &Ah[BUF][m_][0]);  \
    }                                                                           \
  } while (0)

  #define COMPUTE1(BUF) do {                                                    \
    bf16x8 ah_[4], al_[4];                                                      \
    _Pragma("unroll")                                                           \
    for (int mt = 0; mt < 4; ++mt) {                                            \
      ah_[mt] = *(const bf16x8*)&Ah[BUF][mh * 64 + mt * 16 + q][quad * 8];      \
      al_[mt] = *(const bf16x8*)&Al[BUF][mh * 64 + mt * 16 + q][quad * 8];      \
    }                                                                           \
    _Pragma("unroll")                                                           \
    for (int tt = 0; tt < 6; ++tt) {                                            \
      bf16x8 bh = *(const bf16x8*)&WhS[BUF][ng * 96 + tt * 16 + q][quad * 8];   \
      bf16x8 bl = *(const bf16x8*)&WlS[BUF][ng * 96 + tt * 16 + q][quad * 8];   \
      _Pragma("unroll")                                                         \
      for (int mt = 0; mt < 4; ++mt) {                                          \
        acc[mt][tt] = MFMA16(ah_[mt], bh, acc[mt][tt]);                         \
        acc[mt][tt] = MFMA16(ah_[mt], bl, acc[mt][tt]);                         \
        acc[mt][tt] = MFMA16(al_[mt], bh, acc[mt][tt]);                         \
      }                                                                         \
    }                                                                           \
  } while (0)

  #define COMPUTE2(BUF) do {                                                    \
    bf16x8 ah_[4];                                                              \
    _Pragma("unroll")                                                           \
    for (int mt = 0; mt < 4; ++mt)                                              \
      ah_[mt] = *(const bf16x8*)&Ah[BUF][mh * 64 + mt * 16 + q][quad * 8];      \
    _Pragma("unroll")                                                           \
    for (int ti = 0; ti < 6; ++ti) {                                            \
      const int tt = (ti < 4) ? ti : ti + 2;  /* tiles 0,1,2,3,6,7 */           \
      const int wr = ng * 96 + ((tt < 4) ? tt * 16 : 64 + (tt - 6) * 16) + q;   \
      bf16x8 bh = *(const bf16x8*)&WhS[BUF][wr][quad * 8];                      \
      bf16x8 bl = *(const bf16x8*)&WlS[BUF][wr][quad * 8];                      \
      _Pragma("unroll")                                                         \
      for (int mt = 0; mt < 4; ++mt) {                                          \
        acc[mt][tt] = MFMA16(ah_[mt], bh, acc[mt][tt]);                         \
        acc[mt][tt] = MFMA16(ah_[mt], bl, acc[mt][tt]);                         \
      }                                                                         \
    }                                                                           \
  } while (0)

  // prologue: stage chunk 0 entirely (10 ops)
  STAGE_W1(0, 0);
  STAGE_A1(0, 0);
  int buf = 0;
  // ---- phase 1: kc 0..6 — next is phase1-style (10 ops in flight)
  #pragma unroll
  for (int kc = 0; kc < 7; ++kc) {
    STAGE_W1(kc + 1, buf ^ 1);
    STAGE_A1(kc + 1, buf ^ 1);
    KWAITV("10"); KSBAR(); KBAR();
    COMPUTE1(buf);
    KWAITL(); KSBAR(); KBAR();
    buf ^= 1;
  }
  // ---- kc = 7: next is phase-2 style (6 W + 2 A = 8 ops)
  {
    STAGE_W2(8, buf ^ 1);
    STAGE_A2(8, buf ^ 1);
    KWAITV("8"); KSBAR(); KBAR();
    COMPUTE1(buf);
    KWAITL(); KSBAR(); KBAR();
    buf ^= 1;
  }
  // ---- phase 2: kc 8..10 — next 8 ops
  #pragma unroll
  for (int kc = 8; kc < 11; ++kc) {
    STAGE_W2(kc + 1, buf ^ 1);
    STAGE_A2(kc + 1, buf ^ 1);
    KWAITV("8"); KSBAR(); KBAR();
    COMPUTE2(buf);
    KWAITL(); KSBAR(); KBAR();
    buf ^= 1;
  }
  // ---- kc = 11: nothing to prefetch
  {
    KWAITV("0"); KSBAR(); KBAR();
    COMPUTE2(buf);
  }

  // gates epilogue with folded rank-1 biases
  const int jb = nh * 256 + ng * 128;
  float cs[2][4], a1s[2][3], a2s[2][3];
  #pragma unroll
  for (int s = 0; s < 2; ++s) {
    #pragma unroll
    for (int gb = 0; gb < 4; ++gb) cs[s][gb] = cc[jb + (gb * 2 + s) * 16 + q];
    #pragma unroll
    for (int gb = 0; gb < 3; ++gb) {
      a1s[s][gb] = u1v[jb + (gb * 2 + s) * 16 + q];
      a2s[s][gb] = u2v[jb + (gb * 2 + s) * 16 + q];
    }
  }
  #pragma unroll
  for (int mt = 0; mt < 4; ++mt) {
    #pragma unroll
    for (int r = 0; r < 4; ++r) {
      size_t row = rbase + mh * 64 + mt * 16 + quad * 4 + r;
      float rin = rs_in[row], rot = rs_out[row];
      #pragma unroll
      for (int s = 0; s < 2; ++s) {
        int c = nh * 64 + ng * 32 + s * 16 + q;
        float sr  = acc[mt][0 + s][r] + cs[s][0] + rin * a1s[s][0] + rot * a2s[s][0];
        float si  = acc[mt][2 + s][r] + cs[s][1] + rin * a1s[s][1] + rot * a2s[s][1];
        float ani = acc[mt][4 + s][r] + cs[s][2] + rin * a1s[s][2] + rot * a2s[s][2];
        float anh = acc[mt][6 + s][r] + cs[s][3];
        float g_rs = fsigmoid(sr);
        float g_in = fsigmoid(si);
        float g_ot = ftanh(ani + g_rs * anh);
        float h = bf2f(Z_hi[row * 384 + 256 + c]);
        out[row * 128 + c] = g_ot + g_in * (h - g_ot);
      }
    }
  }
  #undef STAGE_W1
  #undef STAGE_W2
  #undef STAGE_A1
  #undef STAGE_A2
  #undef COMPUTE1
  #undef COMPUTE2
}

extern "C" void kernel_launch(void* const* d_in, const int* in_sizes, int n_in,
                              void* d_out, int out_size, void* d_ws, size_t ws_size,
                              hipStream_t stream) {
  const int*   x     = (const int*)d_in[0];
  const float* A     = (const float*)d_in[1];
  const float* emb   = (const float*)d_in[2];
  const float* w_in  = (const float*)d_in[3];
  const float* b_in  = (const float*)d_in[4];
  const float* w_out = (const float*)d_in[5];
  const float* b_out = (const float*)d_in[6];
  const float* w_ih  = (const float*)d_in[7];
  const float* b_ih  = (const float*)d_in[8];
  const float* w_hh  = (const float*)d_in[9];
  const float* b_hh  = (const float*)d_in[10];
  const float* b_iah = (const float*)d_in[11];
  const float* b_oah = (const float*)d_in[12];
  float* out = (float*)d_out;
  char* ws = (char*)d_ws;

  if (ws_size < WS_BYTES) return;

  unsigned short* Z_hi = (unsigned short*)(ws + OFF_ZHI);
  unsigned short* Z_lo = (unsigned short*)(ws + OFF_ZLO);
  unsigned short* hT   = (unsigned short*)(ws + OFF_HT);
  float* M1 = (float*)(ws + OFF_M1);
  float* M2 = (float*)(ws + OFF_M2);
  unsigned short* Wh = (unsigned short*)(ws + OFF_WH);
  unsigned short* Wl = (unsigned short*)(ws + OFF_WL);
  float* ccv = (float*)(ws + OFF_CC);
  float* u1v = (float*)(ws + OFF_U1V);
  float* u2v = (float*)(ws + OFF_U2V);
  float* u1  = (float*)(ws + OFF_U1);
  float* u2  = (float*)(ws + OFF_U2);
  float* c0  = (float*)(ws + OFF_C0);
  float* rs_in  = (float*)(ws + OFF_RSI);
  float* rs_out = (float*)(ws + OFF_RSO);

  kprep<<<384, 128, 0, stream>>>(w_ih, w_in, w_out, b_in, b_out, b_iah, b_oah,
                                 b_ih, M1, M2, u1, u2, c0);
  wcat_build<<<(512 * 384 + 255) / 256, 256, 0, stream>>>(M1, M2, w_hh, b_hh,
                                                          u1, u2, c0, Wh, Wl,
                                                          ccv, u1v, u2v);
  dim3 g1(BB, 7);
  k1_gather<<<g1, 256, 0, stream>>>(x, emb, hT, Z_hi);
  dim3 g2(BB, 4);
  k2_amm<<<g2, 256, 0, stream>>>(A, hT, Z_hi, Z_lo, rs_in, rs_out);
  dim3 g3(BNROWS / 128, 2);
  k3_gates<<<g3, 256, 0, stream>>>(Z_hi, Z_lo, Wh, Wl, ccv, u1v, u2v,
                                   rs_in, rs_out, out);
}

// Round 8
// 491.281 us; speedup vs baseline: 1.0265x; 1.0093x over previous
//
#include <hip/hip_runtime.h>
#include <math.h>

#define BB 512
#define NN 200
#define DD 128
#define BNROWS (BB*NN)   // 102400

typedef float f32x4 __attribute__((ext_vector_type(4)));
typedef short bf16x8 __attribute__((ext_vector_type(8)));
typedef unsigned short u16x4 __attribute__((ext_vector_type(4)));

#define MFMA16(a,b,c) __builtin_amdgcn_mfma_f32_16x16x32_bf16(a,b,c,0,0,0)

// async global -> LDS, 16B per lane. LDS dest is WAVE-UNIFORM base; HW adds lane*16.
#define GLL(gp, lp) __builtin_amdgcn_global_load_lds( \
    (const __attribute__((address_space(1))) unsigned int*)(gp), \
    (__attribute__((address_space(3))) unsigned int*)(lp), 16, 0, 0)

#define KWAITV(S) asm volatile("s_waitcnt vmcnt(" S ")" ::: "memory")
#define KWAITL()  asm volatile("s_waitcnt lgkmcnt(0)" ::: "memory")
#define KBAR()    __builtin_amdgcn_s_barrier()
#define KSBAR()   __builtin_amdgcn_sched_barrier(0)

// ---------------- workspace layout (bytes) ----------------
#define OFF_ZHI   ((size_t)0)
#define OFF_ZLO   (OFF_ZHI + (size_t)BNROWS*384*2)
#define OFF_HT    (OFF_ZLO + (size_t)BNROWS*256*2)
#define OFF_M1    (OFF_HT  + (size_t)BB*128*224*2)
#define OFF_M2    (OFF_M1  + (size_t)384*128*4)
#define OFF_WH    (OFF_M2  + (size_t)384*128*4)
#define OFF_WL    (OFF_WH  + (size_t)512*384*2)
#define OFF_CC    (OFF_WL  + (size_t)512*384*2)
#define OFF_U1V   (OFF_CC  + 512*4)
#define OFF_U2V   (OFF_U1V + 512*4)
#define OFF_U1    (OFF_U2V + 512*4)
#define OFF_U2    (OFF_U1  + 384*4)
#define OFF_C0    (OFF_U2  + 384*4)
#define OFF_RSI   (OFF_C0  + 384*4)
#define OFF_RSO   (OFF_RSI + (size_t)BNROWS*4)
#define WS_BYTES  (OFF_RSO + (size_t)BNROWS*4)

__device__ inline unsigned short f2bf(float x) {
  unsigned int u = __float_as_uint(x);
  unsigned int r = u + 0x7FFFu + ((u >> 16) & 1u);   // RNE
  return (unsigned short)(r >> 16);
}
__device__ inline float bf2f(unsigned short h) {
  return __uint_as_float(((unsigned int)h) << 16);
}
__device__ inline float fsigmoid(float x) {
  return 1.f / (1.f + __expf(-x));
}
__device__ inline float ftanh(float x) {
  x = fminf(15.f, fmaxf(-15.f, x));   // avoid inf/inf
  float e = __expf(-2.f * x);
  return (1.f - e) / (1.f + e);
}

// ---------------- kprep: M1 = W1 @ w_in, M2 = W2 @ w_out; u1,u2,c0 vectors ----
__global__ __launch_bounds__(128) void kprep(
    const float* __restrict__ w_ih, const float* __restrict__ w_in,
    const float* __restrict__ w_out, const float* __restrict__ b_in,
    const float* __restrict__ b_out, const float* __restrict__ b_iah,
    const float* __restrict__ b_oah, const float* __restrict__ b_ih,
    float* __restrict__ M1, float* __restrict__ M2,
    float* __restrict__ u1, float* __restrict__ u2, float* __restrict__ c0) {
  __shared__ float wrow[256];
  const int j = blockIdx.x;        // 0..383
  const int k = threadIdx.x;       // 0..127
  wrow[k]       = w_ih[(size_t)j * 256 + k];
  wrow[128 + k] = w_ih[(size_t)j * 256 + 128 + k];
  __syncthreads();
  float a1 = 0.f, a2 = 0.f;
  for (int t = 0; t < 128; ++t) {
    a1 = fmaf(wrow[t],       w_in[t * 128 + k],  a1);
    a2 = fmaf(wrow[128 + t], w_out[t * 128 + k], a2);
  }
  M1[j * 128 + k] = a1;
  M2[j * 128 + k] = a2;
  if (k == 0) {
    float s1 = 0.f, s2 = 0.f, s0 = 0.f;
    for (int t = 0; t < 128; ++t) {
      s1 = fmaf(wrow[t], b_in[t], s1);
      s2 = fmaf(wrow[128 + t], b_out[t], s2);
      s0 = fmaf(wrow[t], b_iah[t], s0);
      s0 = fmaf(wrow[128 + t], b_oah[t], s0);
    }
    u1[j] = s1; u2[j] = s2; c0[j] = s0 + b_ih[j];
  }
}

// ---------------- Wcat build: FRAGMENT-MAJOR tiled layout ----------------------
// Wh/Wl element index: idx = (((nh*2+ng)*12 + kc)*8 + tt)*512 + lane*8 + e,
// lane = quad*16 + q, value = Wcat[nh*256+ng*128+tt*16+q][kc*32+quad*8+e].
// GLL of one 1KB tile is a contiguous global read AND yields the MFMA B-frag of
// lane l at LDS offset l*16 -> contiguous (conflict-free) ds_read_b128.
__global__ void wcat_build(const float* __restrict__ M1, const float* __restrict__ M2,
                           const float* __restrict__ w_hh, const float* __restrict__ b_hh,
                           const float* __restrict__ u1, const float* __restrict__ u2,
                           const float* __restrict__ c0,
                           unsigned short* __restrict__ Wh, unsigned short* __restrict__ Wl,
                           float* __restrict__ cc, float* __restrict__ u1v,
                           float* __restrict__ u2v) {
  int idx = blockIdx.x * 256 + threadIdx.x;   // 512*384 elems
  if (idx >= 512 * 384) return;
  int e = idx & 7;
  int lane = (idx >> 3) & 63;
  int q = lane & 15, quad = lane >> 4;
  int tl = idx >> 9;            // 0..383 tile linear
  int tt = tl & 7;
  int kcng = tl >> 3;           // 0..47
  int kc = kcng % 12;
  int nhng = kcng / 12;         // 0..3
  int ng = nhng & 1, nh = nhng >> 1;
  int blk = tt >> 1, s = tt & 1;
  int c = nh * 64 + ng * 32 + s * 16 + q;
  int g = (blk <= 1) ? blk : 2;
  int j = g * 128 + c;
  int k = kc * 32 + quad * 8 + e;
  float val;
  if (k < 128)      val = (blk == 3) ? 0.f : M1[j * 128 + k];
  else if (k < 256) val = (blk == 3) ? 0.f : M2[j * 128 + (k - 128)];
  else              val = (blk == 2) ? 0.f : w_hh[(size_t)j * 128 + (k - 256)];
  unsigned short h = f2bf(val);
  Wh[idx] = h;
  Wl[idx] = f2bf(val - bf2f(h));
  if (kc == 0 && quad == 0 && e == 0) {
    int jp = nh * 256 + ng * 128 + tt * 16 + q;
    float ccv, a1, a2;
    if (blk == 0)      { ccv = c0[c] + b_hh[c];             a1 = u1[c];       a2 = u2[c]; }
    else if (blk == 1) { ccv = c0[128 + c] + b_hh[128 + c]; a1 = u1[128 + c]; a2 = u2[128 + c]; }
    else if (blk == 2) { ccv = c0[256 + c];                 a1 = u1[256 + c]; a2 = u2[256 + c]; }
    else               { ccv = b_hh[256 + c];               a1 = 0.f;         a2 = 0.f; }
    cc[jp] = ccv; u1v[jp] = a1; u2v[jp] = a2;
  }
}

// ---------------- K1: emb gather -> Z_hi hidden cols + transposed bf16 HT -----
__global__ __launch_bounds__(256) void k1_gather(
    const int* __restrict__ x, const float* __restrict__ emb,
    unsigned short* __restrict__ hT, unsigned short* __restrict__ Z_hi) {
  __shared__ float hid[32][132];
  const int t = threadIdx.x;
  const int b = blockIdx.x;
  const int m0 = blockIdx.y * 32;
  for (int i = t; i < 32 * 128; i += 256) {
    int r = i >> 7, c = i & 127;
    int m = m0 + r;
    int rowc = b * 200 + (m < 200 ? m : 199);
    float h = emb[(size_t)x[rowc] * 128 + c];
    hid[r][c] = h;
    if (m < 200) Z_hi[(size_t)(b * 200 + m) * 384 + 256 + c] = f2bf(h);
  }
  __syncthreads();
  {
    int c = t >> 1, half = t & 1;
    bf16x8 p0, p1;
    #pragma unroll
    for (int j = 0; j < 16; ++j) {
      int ml = half * 16 + j;
      bool valid = (m0 + ml) < 200;
      float fv = valid ? hid[ml][c] : 0.f;
      if (j < 8) p0[j] = (short)f2bf(fv);
      else       p1[j - 8] = (short)f2bf(fv);
    }
    size_t base = ((size_t)(b * 128 + c)) * 224 + m0 + half * 16;
    *(bf16x8*)&hT[base]     = p0;
    *(bf16x8*)&hT[base + 8] = p1;
  }
}

// ---------------- K2: P = A @ H via MFMA, pipelined (counted vmcnt) -----------
__global__ __launch_bounds__(256, 2) void k2_amm(
    const float* __restrict__ A, const unsigned short* __restrict__ hT,
    unsigned short* __restrict__ Z_hi, unsigned short* __restrict__ Z_lo,
    float* __restrict__ rs_in, float* __restrict__ rs_out) {
  __shared__ alignas(16) unsigned short Ainh[2][64][40];   // padded rows: 80B
  __shared__ alignas(16) unsigned short Ainl[2][64][40];
  __shared__ alignas(16) unsigned short Aouth[2][64][40];
  __shared__ alignas(16) unsigned short Aoutl[2][64][40];
  __shared__ alignas(16) unsigned short Bv[2][128][32];    // linear (GLL dest)
  const int t = threadIdx.x;
  const int b = blockIdx.x;
  const int m0 = blockIdx.y * 64;
  const int wv = t >> 6, lane = t & 63;
  const int q = lane & 15, quad = lane >> 4;
  const int sel = wv >> 1, nh2 = wv & 1;
  const int lrow = lane >> 2, lseg = lane & 3;
  const int sx8 = (lseg ^ ((lrow >> 1) & 3)) * 8;   // swizzled source slot (elems)
  const int qs8 = (quad ^ ((q >> 1) & 3)) * 8;      // swizzled read slot (elems)

  const int am = t >> 2, aseg = t & 3;
  const int gm = m0 + am;
  const bool mvalid = gm < 200;
  const float* arow = A + (size_t)(b * 200 + (mvalid ? gm : 199)) * 400;

  f32x4 acc[4][4];
  #pragma unroll
  for (int i = 0; i < 4; ++i)
    #pragma unroll
    for (int j = 0; j < 4; ++j) acc[i][j] = 0.f;
  float rsi = 0.f, rso = 0.f;

  #define AISSUE(K0, P0, P1, Q0, Q1) do {                                       \
    int kb_ = (K0) + aseg * 8;                                                  \
    int kc_ = (kb_ < 200) ? kb_ : 0;                                            \
    P0 = *(const f32x4*)(arow + kc_);                                           \
    P1 = *(const f32x4*)(arow + kc_ + 4);                                       \
    Q0 = *(const f32x4*)(arow + 200 + kc_);                                     \
    Q1 = *(const f32x4*)(arow + 200 + kc_ + 4);                                 \
  } while (0)

  #define STAGE_B(K0, BUF) do {                                                 \
    _Pragma("unroll")                                                           \
    for (int op_ = 0; op_ < 2; ++op_) {                                         \
      int j_ = wv * 32 + op_ * 16 + lrow;                                       \
      int c_ = ((j_ >> 6) << 6) + ((j_ & 15) << 2) + ((j_ >> 4) & 3);           \
      GLL(hT + ((size_t)(b * 128 + c_)) * 224 + (K0) + sx8,                     \
          &Bv[BUF][wv * 32 + op_ * 16][0]);                                     \
    }                                                                           \
  } while (0)

  #define ACONV(K0, BUF, P0, P1, Q0, Q1) do {                                   \
    bool kv_ = mvalid && ((K0) + aseg * 8 < 200);                               \
    float fin_[8], fot_[8];                                                     \
    fin_[0]=P0.x; fin_[1]=P0.y; fin_[2]=P0.z; fin_[3]=P0.w;                     \
    fin_[4]=P1.x; fin_[5]=P1.y; fin_[6]=P1.z; fin_[7]=P1.w;                     \
    fot_[0]=Q0.x; fot_[1]=Q0.y; fot_[2]=Q0.z; fot_[3]=Q0.w;                     \
    fot_[4]=Q1.x; fot_[5]=Q1.y; fot_[6]=Q1.z; fot_[7]=Q1.w;                     \
    bf16x8 ih_, il_, oh_, ol_;                                                  \
    _Pragma("unroll")                                                           \
    for (int e_ = 0; e_ < 8; ++e_) {                                            \
      float fi_ = kv_ ? fin_[e_] : 0.f;                                         \
      float fo_ = kv_ ? fot_[e_] : 0.f;                                         \
      rsi += fi_; rso += fo_;                                                   \
      unsigned short h1_ = f2bf(fi_);                                           \
      ih_[e_] = (short)h1_; il_[e_] = (short)f2bf(fi_ - bf2f(h1_));             \
      unsigned short h2_ = f2bf(fo_);                                           \
      oh_[e_] = (short)h2_; ol_[e_] = (short)f2bf(fo_ - bf2f(h2_));             \
    }                                                                           \
    *(bf16x8*)&Ainh[BUF][am][aseg * 8]  = ih_;                                  \
    *(bf16x8*)&Ainl[BUF][am][aseg * 8]  = il_;                                  \
    *(bf16x8*)&Aouth[BUF][am][aseg * 8] = oh_;                                  \
    *(bf16x8*)&Aoutl[BUF][am][aseg * 8] = ol_;                                  \
  } while (0)

  #define K2COMP(BUF) do {                                                      \
    const unsigned short (*Ath_)[40] = sel ? Aouth[BUF] : Ainh[BUF];            \
    const unsigned short (*Atl_)[40] = sel ? Aoutl[BUF] : Ainl[BUF];            \
    bf16x8 ah_[4], al_[4];                                                      \
    _Pragma("unroll")                                                           \
    for (int mt = 0; mt < 4; ++mt) {                                            \
      ah_[mt] = *(const bf16x8*)&Ath_[mt * 16 + q][quad * 8];                   \
      al_[mt] = *(const bf16x8*)&Atl_[mt * 16 + q][quad * 8];                   \
    }                                                                           \
    _Pragma("unroll")                                                           \
    for (int nt = 0; nt < 4; ++nt) {                                            \
      bf16x8 bb_ = *(const bf16x8*)&Bv[BUF][nh2 * 64 + nt * 16 + q][qs8];       \
      _Pragma("unroll")                                                         \
      for (int mt = 0; mt < 4; ++mt) {                                          \
        acc[mt][nt] = MFMA16(ah_[mt], bb_, acc[mt][nt]);                        \
        acc[mt][nt] = MFMA16(al_[mt], bb_, acc[mt][nt]);                        \
      }                                                                         \
    }                                                                           \
  } while (0)

  f32x4 cp0, cp1, cq0, cq1;
  AISSUE(0, cp0, cp1, cq0, cq1);
  STAGE_B(0, 0);
  int buf = 0;

  for (int k = 0; k < 6; ++k) {
    const int k0n = (k + 1) * 32;
    f32x4 np0, np1, nq0, nq1;
    AISSUE(k0n, np0, np1, nq0, nq1);
    STAGE_B(k0n, buf ^ 1);
    KWAITV("6"); KSBAR();                 // A(k),B(k) drained; 6 newer in flight
    ACONV(k * 32, buf, cp0, cp1, cq0, cq1);
    KWAITL(); KSBAR(); KBAR();
    K2COMP(buf);
    KBAR();                               // protect Bv[buf] before next GLL
    cp0 = np0; cp1 = np1; cq0 = nq0; cq1 = nq1;
    buf ^= 1;
  }
  KWAITV("0"); KSBAR();
  ACONV(192, buf, cp0, cp1, cq0, cq1);
  KWAITL(); KSBAR(); KBAR();
  K2COMP(buf);

  const int colb = sel * 128 + nh2 * 64 + q * 4;
  #pragma unroll
  for (int mt = 0; mt < 4; ++mt) {
    #pragma unroll
    for (int r = 0; r < 4; ++r) {
      int m = m0 + mt * 16 + quad * 4 + r;
      if (m < 200) {
        u16x4 h4, l4;
        #pragma unroll
        for (int nt = 0; nt < 4; ++nt) {
          float v = acc[mt][nt][r];
          unsigned short hs = f2bf(v);
          h4[nt] = hs;
          l4[nt] = f2bf(v - bf2f(hs));
        }
        size_t row = (size_t)(b * 200 + m);
        *(u16x4*)&Z_hi[row * 384 + colb] = h4;
        *(u16x4*)&Z_lo[row * 256 + colb] = l4;
      }
    }
  }
  rsi += __shfl_xor(rsi, 1); rsi += __shfl_xor(rsi, 2);
  rso += __shfl_xor(rso, 1); rso += __shfl_xor(rso, 2);
  if (aseg == 0 && mvalid) {
    rs_in[(size_t)b * 200 + gm]  = rsi;
    rs_out[(size_t)b * 200 + gm] = rso;
  }
  #undef AISSUE
  #undef STAGE_B
  #undef ACONV
  #undef K2COMP
}

// ---------------- K3: dbuf GLL pipeline, fragment-major W tiles + gates -------
// W staged as 1KB fragment-major tiles (contiguous global read; LDS frag of
// lane l at l*16 -> conflict-free ds_read_b128). A-tiles keep linear layout
// (shared with k2's coalesced writes). Depth-2 prefetch both W and A.
__global__ __launch_bounds__(256, 2) void k3_gates(
    const unsigned short* __restrict__ Z_hi, const unsigned short* __restrict__ Z_lo,
    const unsigned short* __restrict__ Wh, const unsigned short* __restrict__ Wl,
    const float* __restrict__ cc, const float* __restrict__ u1v,
    const float* __restrict__ u2v, const float* __restrict__ rs_in,
    const float* __restrict__ rs_out, float* __restrict__ out) {
  __shared__ alignas(16) unsigned short WhS[2][12][512];   // 24 KB (dbuf, tiles)
  __shared__ alignas(16) unsigned short WlS[2][12][512];   // 24 KB
  __shared__ alignas(16) unsigned short Ah[2][128][32];    // 16 KB (dbuf)
  __shared__ alignas(16) unsigned short Al[2][128][32];    // 16 KB (dbuf)
  const int t = threadIdx.x;
  const int w = t >> 6, lane = t & 63;
  const int q = lane & 15, quad = lane >> 4;
  const int mh = w >> 1, ng = w & 1;
  const int lrow = lane >> 2, lseg = lane & 3;
  const size_t rbase = (size_t)blockIdx.x * 128;
  const int nh = blockIdx.y;

  f32x4 acc[4][8];
  #pragma unroll
  for (int i = 0; i < 4; ++i)
    #pragma unroll
    for (int j = 0; j < 8; ++j) acc[i][j] = 0.f;

  // wave w stages hi+lo tiles ti = 3w..3w+2 (ti in [0,12): ng_t=ti/6, tt_t=ti%6)
  #define STAGE_W1(KC, BUF) do {                                                \
    _Pragma("unroll")                                                           \
    for (int i_ = 0; i_ < 3; ++i_) {                                            \
      int ti_ = w * 3 + i_;                                                     \
      int ngt_ = (ti_ >= 6) ? 1 : 0;                                            \
      int ttt_ = ti_ - ngt_ * 6;                                                \
      size_t src_ = ((size_t)(((nh * 2 + ngt_) * 12 + (KC)) * 8 + ttt_)) * 512; \
      GLL(Wh + src_ + lane * 8, &WhS[BUF][ti_][0]);                             \
    }                                                                           \
    _Pragma("unroll")                                                           \
    for (int i_ = 0; i_ < 3; ++i_) {                                            \
      int ti_ = w * 3 + i_;                                                     \
      int ngt_ = (ti_ >= 6) ? 1 : 0;                                            \
      int ttt_ = ti_ - ngt_ * 6;                                                \
      size_t src_ = ((size_t)(((nh * 2 + ngt_) * 12 + (KC)) * 8 + ttt_)) * 512; \
      GLL(Wl + src_ + lane * 8, &WlS[BUF][ti_][0]);                             \
    }                                                                           \
  } while (0)

  // phase2 tile set {0,1,2,3,6,7}: slot i holds tt = (i<4)?i:i+2
  #define STAGE_W2(KC, BUF) do {                                                \
    _Pragma("unroll")                                                           \
    for (int i_ = 0; i_ < 3; ++i_) {                                            \
      int ti_ = w * 3 + i_;                                                     \
      int ngt_ = (ti_ >= 6) ? 1 : 0;                                            \
      int tts_ = ti_ - ngt_ * 6;                                                \
      int ttg_ = (tts_ < 4) ? tts_ : tts_ + 2;                                  \
      size_t src_ = ((size_t)(((nh * 2 + ngt_) * 12 + (KC)) * 8 + ttg_)) * 512; \
      GLL(Wh + src_ + lane * 8, &WhS[BUF][ti_][0]);                             \
    }                                                                           \
    _Pragma("unroll")                                                           \
    for (int i_ = 0; i_ < 3; ++i_) {                                            \
      int ti_ = w * 3 + i_;                                                     \
      int ngt_ = (ti_ >= 6) ? 1 : 0;                                            \
      int tts_ = ti_ - ngt_ * 6;                                                \
      int ttg_ = (tts_ < 4) ? tts_ : tts_ + 2;                                  \
      size_t src_ = ((size_t)(((nh * 2 + ngt_) * 12 + (KC)) * 8 + ttg_)) * 512; \
      GLL(Wl + src_ + lane * 8, &WlS[BUF][ti_][0]);                             \
    }                                                                           \
  } while (0)

  #define STAGE_A1(KC, BUF) do {                                                \
    const int k0_ = (KC) * 32;                                                  \
    _Pragma("unroll")                                                           \
    for (int c_ = 0; c_ < 2; ++c_) {                                            \
      int m_ = w * 32 + c_ * 16;                                                \
      GLL(Z_hi + (rbase + m_ + lrow) * 384 + k0_ + lseg * 8, &Ah[BUF][m_][0]);  \
    }                                                                           \
    _Pragma("unroll")                                                           \
    for (int c_ = 0; c_ < 2; ++c_) {                                            \
      int m_ = w * 32 + c_ * 16;                                                \
      GLL(Z_lo + (rbase + m_ + lrow) * 256 + k0_ + lseg * 8, &Al[BUF][m_][0]);  \
    }                                                                           \
  } while (0)

  #define STAGE_A2(KC, BUF) do {                                                \
    const int k0_ = (KC) * 32;                                                  \
    _Pragma("unroll")                                                           \
    for (int c_ = 0; c_ < 2; ++c_) {                                            \
      int m_ = w * 32 + c_ * 16;                                                \
      GLL(Z_hi + (rbase + m_ + lrow) * 384 + k0_ + lseg * 8, &Ah[BUF][m_][0]);  \
    }                                                                           \
  } while (0)

  #define COMPUTE1(BUF) do {                                                    \
    bf16x8 ah_[4], al_[4];                                                      \
    _Pragma("unroll")                                                           \
    for (int mt = 0; mt < 4; ++mt) {                                            \
      ah_[mt] = *(const bf16x8*)&Ah[BUF][mh * 64 + mt * 16 + q][quad * 8];      \
      al_[mt] = *(const bf16x8*)&Al[BUF][mh * 64 + mt * 16 + q][quad * 8];      \
    }                                                                           \
    _Pragma("unroll")                                                           \
    for (int tt = 0; tt < 6; ++tt) {                                            \
      bf16x8 bh = *(const bf16x8*)&WhS[BUF][ng * 6 + tt][lane * 8];             \
      bf16x8 bl = *(const bf16x8*)&WlS[BUF][ng * 6 + tt][lane * 8];             \
      _Pragma("unroll")                                                         \
      for (int mt = 0; mt < 4; ++mt) {                                          \
        acc[mt][tt] = MFMA16(ah_[mt], bh, acc[mt][tt]);                         \
        acc[mt][tt] = MFMA16(ah_[mt], bl, acc[mt][tt]);                         \
        acc[mt][tt] = MFMA16(al_[mt], bh, acc[mt][tt]);                         \
      }                                                                         \
    }                                                                           \
  } while (0)

  #define COMPUTE2(BUF) do {                                                    \
    bf16x8 ah_[4];                                                              \
    _Pragma("unroll")                                                           \
    for (int mt = 0; mt < 4; ++mt)                                              \
      ah_[mt] = *(const bf16x8*)&Ah[BUF][mh * 64 + mt * 16 + q][quad * 8];      \
    _Pragma("unroll")                                                           \
    for (int ti = 0; ti < 6; ++ti) {                                            \
      const int tt = (ti < 4) ? ti : ti + 2;  /* acc tile 0,1,2,3,6,7 */        \
      bf16x8 bh = *(const bf16x8*)&WhS[BUF][ng * 6 + ti][lane * 8];             \
      bf16x8 bl = *(const bf16x8*)&WlS[BUF][ng * 6 + ti][lane * 8];             \
      _Pragma("unroll")                                                         \
      for (int mt = 0; mt < 4; ++mt) {                                          \
        acc[mt][tt] = MFMA16(ah_[mt], bh, acc[mt][tt]);                         \
        acc[mt][tt] = MFMA16(ah_[mt], bl, acc[mt][tt]);                         \
      }                                                                         \
    }                                                                           \
  } while (0)

  // prologue: stage chunk 0 entirely (10 ops/wave)
  STAGE_W1(0, 0);
  STAGE_A1(0, 0);
  int buf = 0;
  // ---- phase 1: kc 0..6 — next is phase1-style (10 ops in flight)
  #pragma unroll
  for (int kc = 0; kc < 7; ++kc) {
    STAGE_W1(kc + 1, buf ^ 1);
    STAGE_A1(kc + 1, buf ^ 1);
    KWAITV("10"); KSBAR(); KBAR();
    COMPUTE1(buf);
    KWAITL(); KSBAR(); KBAR();
    buf ^= 1;
  }
  // ---- kc = 7: next is phase-2 style (6 W + 2 A = 8 ops)
  {
    STAGE_W2(8, buf ^ 1);
    STAGE_A2(8, buf ^ 1);
    KWAITV("8"); KSBAR(); KBAR();
    COMPUTE1(buf);
    KWAITL(); KSBAR(); KBAR();
    buf ^= 1;
  }
  // ---- phase 2: kc 8..10 — next 8 ops
  #pragma unroll
  for (int kc = 8; kc < 11; ++kc) {
    STAGE_W2(kc + 1, buf ^ 1);
    STAGE_A2(kc + 1, buf ^ 1);
    KWAITV("8"); KSBAR(); KBAR();
    COMPUTE2(buf);
    KWAITL(); KSBAR(); KBAR();
    buf ^= 1;
  }
  // ---- kc = 11: nothing to prefetch
  {
    KWAITV("0"); KSBAR(); KBAR();
    COMPUTE2(buf);
  }

  // gates epilogue with folded rank-1 biases
  const int jb = nh * 256 + ng * 128;
  float cs[2][4], a1s[2][3], a2s[2][3];
  #pragma unroll
  for (int s = 0; s < 2; ++s) {
    #pragma unroll
    for (int gb = 0; gb < 4; ++gb) cs[s][gb] = cc[jb + (gb * 2 + s) * 16 + q];
    #pragma unroll
    for (int gb = 0; gb < 3; ++gb) {
      a1s[s][gb] = u1v[jb + (gb * 2 + s) * 16 + q];
      a2s[s][gb] = u2v[jb + (gb * 2 + s) * 16 + q];
    }
  }
  #pragma unroll
  for (int mt = 0; mt < 4; ++mt) {
    #pragma unroll
    for (int r = 0; r < 4; ++r) {
      size_t row = rbase + mh * 64 + mt * 16 + quad * 4 + r;
      float rin = rs_in[row], rot = rs_out[row];
      #pragma unroll
      for (int s = 0; s < 2; ++s) {
        int c = nh * 64 + ng * 32 + s * 16 + q;
        float sr  = acc[mt][0 + s][r] + cs[s][0] + rin * a1s[s][0] + rot * a2s[s][0];
        float si  = acc[mt][2 + s][r] + cs[s][1] + rin * a1s[s][1] + rot * a2s[s][1];
        float ani = acc[mt][4 + s][r] + cs[s][2] + rin * a1s[s][2] + rot * a2s[s][2];
        float anh = acc[mt][6 + s][r] + cs[s][3];
        float g_rs = fsigmoid(sr);
        float g_in = fsigmoid(si);
        float g_ot = ftanh(ani + g_rs * anh);
        float h = bf2f(Z_hi[row * 384 + 256 + c]);
        out[row * 128 + c] = g_ot + g_in * (h - g_ot);
      }
    }
  }
  #undef STAGE_W1
  #undef STAGE_W2
  #undef STAGE_A1
  #undef STAGE_A2
  #undef COMPUTE1
  #undef COMPUTE2
}

extern "C" void kernel_launch(void* const* d_in, const int* in_sizes, int n_in,
                              void* d_out, int out_size, void* d_ws, size_t ws_size,
                              hipStream_t stream) {
  const int*   x     = (const int*)d_in[0];
  const float* A     = (const float*)d_in[1];
  const float* emb   = (const float*)d_in[2];
  const float* w_in  = (const float*)d_in[3];
  const float* b_in  = (const float*)d_in[4];
  const float* w_out = (const float*)d_in[5];
  const float* b_out = (const float*)d_in[6];
  const float* w_ih  = (const float*)d_in[7];
  const float* b_ih  = (const float*)d_in[8];
  const float* w_hh  = (const float*)d_in[9];
  const float* b_hh  = (const float*)d_in[10];
  const float* b_iah = (const float*)d_in[11];
  const float* b_oah = (const float*)d_in[12];
  float* out = (float*)d_out;
  char* ws = (char*)d_ws;

  if (ws_size < WS_BYTES) return;

  unsigned short* Z_hi = (unsigned short*)(ws + OFF_ZHI);
  unsigned short* Z_lo = (unsigned short*)(ws + OFF_ZLO);
  unsigned short* hT   = (unsigned short*)(ws + OFF_HT);
  float* M1 = (float*)(ws + OFF_M1);
  float* M2 = (float*)(ws + OFF_M2);
  unsigned short* Wh = (unsigned short*)(ws + OFF_WH);
  unsigned short* Wl = (unsigned short*)(ws + OFF_WL);
  float* ccv = (float*)(ws + OFF_CC);
  float* u1v = (float*)(ws + OFF_U1V);
  float* u2v = (float*)(ws + OFF_U2V);
  float* u1  = (float*)(ws + OFF_U1);
  float* u2  = (float*)(ws + OFF_U2);
  float* c0  = (float*)(ws + OFF_C0);
  float* rs_in  = (float*)(ws + OFF_RSI);
  float* rs_out = (float*)(ws + OFF_RSO);

  kprep<<<384, 128, 0, stream>>>(w_ih, w_in, w_out, b_in, b_out, b_iah, b_oah,
                                 b_ih, M1, M2, u1, u2, c0);
  wcat_build<<<(512 * 384 + 255) / 256, 256, 0, stream>>>(M1, M2, w_hh, b_hh,
                                                          u1, u2, c0, Wh, Wl,
                                                          ccv, u1v, u2v);
  dim3 g1(BB, 7);
  k1_gather<<<g1, 256, 0, stream>>>(x, emb, hT, Z_hi);
  dim3 g2(BB, 4);
  k2_amm<<<g2, 256, 0, stream>>>(A, hT, Z_hi, Z_lo, rs_in, rs_out);
  dim3 g3(BNROWS / 128, 2);
  k3_gates<<<g3, 256, 0, stream>>>(Z_hi, Z_lo, Wh, Wl, ccv, u1v, u2v,
                                   rs_in, rs_out, out);
}